// Round 3
// baseline (680.975 us; speedup 1.0000x reference)
//
#include <hip/hip_runtime.h>
#include <hip/hip_bf16.h>
#include <math.h>

#define NT    4096
#define DM    768
#define HD    3072
#define NE    8
#define CAP   2048
// total compact h rows: sum(roundup(min(cnt,CAP),128)) <= 8192 + 8*127 -> 9216
#define SLOTS_MAX 9216

typedef __attribute__((ext_vector_type(8))) short bf16x8;
typedef __attribute__((ext_vector_type(4))) float f32x4;

__device__ __forceinline__ unsigned short f2bf(float f) {
  unsigned int u = __float_as_uint(f);
  unsigned int r = (u + 0x7fffu + ((u >> 16) & 1u)) >> 16;
  return (unsigned short)r;
}

__device__ __forceinline__ void async16(const unsigned short* g, unsigned short* l) {
  __builtin_amdgcn_global_load_lds((const __attribute__((address_space(1))) void*)g,
                                   (__attribute__((address_space(3))) void*)l,
                                   16, 0, 0);
}

// ---------------- convert x: fp32 -> bf16 --------------------------------------
__global__ void convert_x_kernel(const float* __restrict__ x,
                                 unsigned short* __restrict__ xb) {
  int i = (blockIdx.x * 256 + threadIdx.x) * 4;
  float4 v = *(const float4*)(x + i);
  uint2 o;
  o.x = (unsigned int)f2bf(v.x) | ((unsigned int)f2bf(v.y) << 16);
  o.y = (unsigned int)f2bf(v.z) | ((unsigned int)f2bf(v.w) << 16);
  *(uint2*)(xb + i) = o;
}

// ------ transpose+convert: dst_bf16[e][c][r] = src_f32[e][r][coloff + c] -------
// grid: (C_sub/64, R_rows/32, NE), block 256. dst row stride = R (elements).
__global__ void transpose_kernel(const float* __restrict__ src,
                                 unsigned short* __restrict__ dst,
                                 int R, int src_stride, int col_off,
                                 size_t src_e_stride, size_t dst_e_stride) {
  __shared__ unsigned short tile[64][34];
  const float* s = src + blockIdx.z * src_e_stride;
  unsigned short* d = dst + blockIdx.z * dst_e_stride;
  const int r0 = blockIdx.y * 32;
  const int c0 = blockIdx.x * 64;
  const int t = threadIdx.x;
#pragma unroll
  for (int i = 0; i < 4; i++) {
    int row = (t >> 5) + i * 8;      // 0..31
    int cu  = t & 31;                // col unit (2 elements)
    const float2 v = *(const float2*)(s + (size_t)(r0 + row) * src_stride + col_off + c0 + cu * 2);
    tile[cu * 2][row]     = f2bf(v.x);
    tile[cu * 2 + 1][row] = f2bf(v.y);
  }
  __syncthreads();
#pragma unroll
  for (int i = 0; i < 4; i++) {
    int drow = (t >> 4) + i * 16;    // 0..63 (source col)
    int ru   = t & 15;
    unsigned int v = *(const unsigned int*)&tile[drow][ru * 2];
    *(unsigned int*)(d + (size_t)(c0 + drow) * R + r0 + ru * 2) = v;
  }
}

// ---------------- gating: logits, top-2, softmax, slot assignment --------------
__global__ void gate_kernel(const float* __restrict__ inp,
                            const float* __restrict__ gw,
                            const float* __restrict__ gb,
                            int* __restrict__ cnt,
                            int* __restrict__ src,
                            float* __restrict__ scale) {
  const int tok  = blockIdx.x * 4 + (threadIdx.x >> 6);
  const int lane = threadIdx.x & 63;
  const float* x = inp + (size_t)tok * DM;
  float acc[NE];
#pragma unroll
  for (int e = 0; e < NE; e++) acc[e] = 0.f;
  for (int d = lane; d < DM; d += 64) {
    float xv = x[d];
    const float4 w0 = *(const float4*)(gw + d * NE);
    const float4 w1v = *(const float4*)(gw + d * NE + 4);
    acc[0] += xv * w0.x; acc[1] += xv * w0.y;
    acc[2] += xv * w0.z; acc[3] += xv * w0.w;
    acc[4] += xv * w1v.x; acc[5] += xv * w1v.y;
    acc[6] += xv * w1v.z; acc[7] += xv * w1v.w;
  }
#pragma unroll
  for (int e = 0; e < NE; e++) {
    float v = acc[e];
#pragma unroll
    for (int m = 32; m > 0; m >>= 1) v += __shfl_xor(v, m, 64);
    acc[e] = v + gb[e];
  }
  if (lane == 0) {
    float bv = -1e30f, sv = -1e30f; int bi = 0, si = 0;
#pragma unroll
    for (int e = 0; e < NE; e++) {
      float v = acc[e];
      if (v > bv)      { sv = bv; si = bi; bv = v; bi = e; }
      else if (v > sv) { sv = v;  si = e; }
    }
    float e1 = expf(sv - bv);
    float s0 = 1.f / (1.f + e1);
    float s1 = e1 / (1.f + e1);
    int p0 = atomicAdd(&cnt[bi], 1);
    if (p0 < CAP) { src[bi * CAP + p0] = tok; scale[bi * CAP + p0] = s0; }
    int p1 = atomicAdd(&cnt[si], 1);
    if (p1 < CAP) { src[si * CAP + p1] = tok; scale[si * CAP + p1] = s1; }
  }
}

// ---------------- base: compact h row offsets per expert ----------------------
__global__ void base_kernel(const int* __restrict__ cnt, int* __restrict__ base) {
  if (threadIdx.x == 0 && blockIdx.x == 0) {
    int b = 0;
    for (int e = 0; e < NE; e++) {
      base[e] = b;
      int c = min(cnt[e], CAP);
      b += (c + 127) & ~127;
    }
  }
}

// ---------------- GEMM1: h_c = gelu(gather(xb) @ w1_chunk + b1) ---------------
// grid: (chunk/128, CAP/128, NE), block 256
__global__ __launch_bounds__(256) void gemm1_kernel(
    const unsigned short* __restrict__ xb,    // [NT][DM] bf16
    const unsigned short* __restrict__ w1t,   // [E][chunk][DM] bf16
    const float* __restrict__ b1,             // [E][HD] fp32
    const int* __restrict__ cnt,
    const int* __restrict__ base,
    const int* __restrict__ src,
    unsigned short* __restrict__ h,           // [SLOTS_MAX][chunk] bf16
    int hoff, int chunk) {
  const int e = blockIdx.z;
  const int count = min(cnt[e], CAP);
  const int m0 = blockIdx.y * 128;
  if (m0 >= count) return;
  const int n0 = blockIdx.x * 128;
  const int hb = base[e];

  __shared__ unsigned short As[128 * 32];   // [m][k]
  __shared__ unsigned short Bs[128 * 32];   // [n][k]

  const int t = threadIdx.x;
  const int lane = t & 63;
  const int wave = t >> 6;
  const int r0 = t >> 2;
  const int kc = (t & 3) * 8;

  const int tok0 = src[e * CAP + m0 + r0];
  const int tok1 = src[e * CAP + m0 + r0 + 64];
  const unsigned short* aptr0 = xb + (size_t)tok0 * DM + kc;
  const unsigned short* aptr1 = xb + (size_t)tok1 * DM + kc;
  const unsigned short* w1e = w1t + (size_t)e * chunk * DM;
  const unsigned short* bptr0 = w1e + (size_t)(n0 + r0) * DM + kc;
  const unsigned short* bptr1 = bptr0 + (size_t)64 * DM;

  unsigned short* as0 = As + (wave * 64) * 8;
  unsigned short* as1 = As + (256 + wave * 64) * 8;
  unsigned short* bs0 = Bs + (wave * 64) * 8;
  unsigned short* bs1 = Bs + (256 + wave * 64) * 8;

  const int wrow = (wave >> 1) * 64;
  const int wcol = (wave & 1) * 64;
  const int lrow = lane & 15;
  const int koff = (lane >> 4) * 8;

  f32x4 acc[4][4];
#pragma unroll
  for (int i = 0; i < 4; i++)
#pragma unroll
    for (int j = 0; j < 4; j++) acc[i][j] = (f32x4){0.f, 0.f, 0.f, 0.f};

  for (int k0 = 0; k0 < DM; k0 += 32) {
    async16(aptr0 + k0, as0);
    async16(aptr1 + k0, as1);
    async16(bptr0 + k0, bs0);
    async16(bptr1 + k0, bs1);
    __syncthreads();
    bf16x8 af[4], bfr[4];
#pragma unroll
    for (int i = 0; i < 4; i++)
      af[i] = *(const bf16x8*)(As + (wrow + i * 16 + lrow) * 32 + koff);
#pragma unroll
    for (int j = 0; j < 4; j++)
      bfr[j] = *(const bf16x8*)(Bs + (wcol + j * 16 + lrow) * 32 + koff);
#pragma unroll
    for (int i = 0; i < 4; i++)
#pragma unroll
      for (int j = 0; j < 4; j++)
        acc[i][j] = __builtin_amdgcn_mfma_f32_16x16x32_bf16(af[i], bfr[j], acc[i][j], 0, 0, 0);
    __syncthreads();
  }

  const int q4 = (lane >> 4) * 4;
  const int c = lane & 15;
  unsigned short* hrow = h + (size_t)(hb + m0) * chunk + n0;
#pragma unroll
  for (int j = 0; j < 4; j++) {
    const float bias = b1[e * HD + hoff + n0 + wcol + j * 16 + c];
#pragma unroll
    for (int i = 0; i < 4; i++) {
#pragma unroll
      for (int r = 0; r < 4; r++) {
        int m = wrow + i * 16 + q4 + r;
        float v = acc[i][j][r] + bias;
        float g = 0.5f * v * (1.f + tanhf(0.7978845608f * (v + 0.044715f * v * v * v)));
        hrow[(size_t)m * chunk + wcol + j * 16 + c] = f2bf(g);
      }
    }
  }
}

// ---------------- GEMM2 partial: out += scale * (h_c @ w2_chunk [+ b2]) -------
// grid: (DM/128, CAP/128, NE), block 256
__global__ __launch_bounds__(256) void gemm2_kernel(
    const unsigned short* __restrict__ h,     // [SLOTS_MAX][chunk] bf16
    const unsigned short* __restrict__ w2t,   // [E][DM][chunk] bf16
    const float* __restrict__ b2,             // [E][DM] fp32
    const int* __restrict__ cnt,
    const int* __restrict__ base,
    const int* __restrict__ src,
    const float* __restrict__ scale,
    float* __restrict__ out,                  // [NT][DM] fp32
    int chunk, int add_b2) {
  const int e = blockIdx.z;
  const int count = min(cnt[e], CAP);
  const int m0 = blockIdx.y * 128;
  if (m0 >= count) return;
  const int n0 = blockIdx.x * 128;
  const int hb = base[e];

  __shared__ unsigned short As[128 * 32];
  __shared__ unsigned short Bs[128 * 32];

  const int t = threadIdx.x;
  const int lane = t & 63;
  const int wave = t >> 6;
  const int r0 = t >> 2;
  const int kc = (t & 3) * 8;

  const unsigned short* aptr0 = h + (size_t)(hb + m0 + r0) * chunk + kc;
  const unsigned short* aptr1 = aptr0 + (size_t)64 * chunk;
  const unsigned short* w2e = w2t + (size_t)e * DM * chunk;
  const unsigned short* bptr0 = w2e + (size_t)(n0 + r0) * chunk + kc;
  const unsigned short* bptr1 = bptr0 + (size_t)64 * chunk;

  unsigned short* as0 = As + (wave * 64) * 8;
  unsigned short* as1 = As + (256 + wave * 64) * 8;
  unsigned short* bs0 = Bs + (wave * 64) * 8;
  unsigned short* bs1 = Bs + (256 + wave * 64) * 8;

  const int wrow = (wave >> 1) * 64;
  const int wcol = (wave & 1) * 64;
  const int lrow = lane & 15;
  const int koff = (lane >> 4) * 8;

  f32x4 acc[4][4];
#pragma unroll
  for (int i = 0; i < 4; i++)
#pragma unroll
    for (int j = 0; j < 4; j++) acc[i][j] = (f32x4){0.f, 0.f, 0.f, 0.f};

  for (int k0 = 0; k0 < chunk; k0 += 32) {
    async16(aptr0 + k0, as0);
    async16(aptr1 + k0, as1);
    async16(bptr0 + k0, bs0);
    async16(bptr1 + k0, bs1);
    __syncthreads();
    bf16x8 af[4], bfr[4];
#pragma unroll
    for (int i = 0; i < 4; i++)
      af[i] = *(const bf16x8*)(As + (wrow + i * 16 + lrow) * 32 + koff);
#pragma unroll
    for (int j = 0; j < 4; j++)
      bfr[j] = *(const bf16x8*)(Bs + (wcol + j * 16 + lrow) * 32 + koff);
#pragma unroll
    for (int i = 0; i < 4; i++)
#pragma unroll
      for (int j = 0; j < 4; j++)
        acc[i][j] = __builtin_amdgcn_mfma_f32_16x16x32_bf16(af[i], bfr[j], acc[i][j], 0, 0, 0);
    __syncthreads();
  }

  const int q4 = (lane >> 4) * 4;
  const int c = lane & 15;
#pragma unroll
  for (int i = 0; i < 4; i++) {
#pragma unroll
    for (int r = 0; r < 4; r++) {
      int m = m0 + wrow + i * 16 + q4 + r;
      float sc = scale[e * CAP + m];
      int tok = src[e * CAP + m];
      float* orow = out + (size_t)tok * DM + n0;
#pragma unroll
      for (int j = 0; j < 4; j++) {
        int n = wcol + j * 16 + c;
        float v = acc[i][j][r];
        if (add_b2) v += b2[e * DM + n0 + n];
        atomicAdd(&orow[n], sc * v);
      }
    }
  }
}

extern "C" void kernel_launch(void* const* d_in, const int* in_sizes, int n_in,
                              void* d_out, int out_size, void* d_ws, size_t ws_size,
                              hipStream_t stream) {
  const float* inp = (const float*)d_in[0];
  const float* gw  = (const float*)d_in[1];
  const float* gb  = (const float*)d_in[2];
  const float* w1  = (const float*)d_in[3];
  const float* b1  = (const float*)d_in[4];
  const float* w2  = (const float*)d_in[5];
  const float* b2  = (const float*)d_in[6];
  float* out = (float*)d_out;

  // pick largest chunk that fits ws
  int chunk = 1024;
  while (chunk > 128) {
    size_t need = 131584 + (size_t)NT * DM * 2 + 2 * (size_t)NE * chunk * DM * 2
                + (size_t)SLOTS_MAX * chunk * 2;
    if (need <= ws_size) break;
    chunk >>= 1;
  }

  char* ws = (char*)d_ws;
  int*   cnt  = (int*)(ws);                         // 32 B
  int*   base = (int*)(ws + 256);                   // 32 B
  int*   srcb = (int*)(ws + 512);                   // 64 KB
  float* scl  = (float*)(ws + 512 + (size_t)NE * CAP * 4);
  size_t off = 131584;
  unsigned short* xb = (unsigned short*)(ws + off);   off += (size_t)NT * DM * 2;
  unsigned short* w1tc = (unsigned short*)(ws + off); off += (size_t)NE * chunk * DM * 2;
  unsigned short* w2tc = (unsigned short*)(ws + off); off += (size_t)NE * chunk * DM * 2;
  unsigned short* hc = (unsigned short*)(ws + off);

  hipMemsetAsync(ws, 0, 131584, stream);            // cnt, base, src, scale
  hipMemsetAsync(out, 0, (size_t)NT * DM * 4, stream);

  convert_x_kernel<<<(NT * DM) / 1024, 256, 0, stream>>>(inp, xb);
  gate_kernel<<<NT / 4, 256, 0, stream>>>(inp, gw, gb, cnt, srcb, scl);
  base_kernel<<<1, 64, 0, stream>>>(cnt, base);

  for (int c = 0; c < HD; c += chunk) {
    // w1 chunk: dst[e][h_local][d] = w1[e][d][c + h_local]
    transpose_kernel<<<dim3(chunk / 64, DM / 32, NE), 256, 0, stream>>>(
        w1, w1tc, DM, HD, c, (size_t)DM * HD, (size_t)chunk * DM);
    // w2 chunk: dst[e][d][h_local] = w2[e][c + h_local][d]
    transpose_kernel<<<dim3(DM / 64, chunk / 32, NE), 256, 0, stream>>>(
        w2 + (size_t)c * DM, w2tc, chunk, DM, 0, (size_t)HD * DM, (size_t)DM * chunk);
    gemm1_kernel<<<dim3(chunk / 128, CAP / 128, NE), 256, 0, stream>>>(
        xb, w1tc, b1, cnt, base, srcb, hc, c, chunk);
    gemm2_kernel<<<dim3(DM / 128, CAP / 128, NE), 256, 0, stream>>>(
        hc, w2tc, b2, cnt, base, srcb, scl, out, chunk, c == 0 ? 1 : 0);
  }
}

// Round 4
// 448.265 us; speedup vs baseline: 1.5191x; 1.5191x over previous
//
#include <hip/hip_runtime.h>
#include <hip/hip_bf16.h>
#include <math.h>

#define NT    4096
#define DM    768
#define HD    3072
#define NE    8
#define CAP   2048
// total compact h rows: sum(roundup(min(cnt,CAP),128)) <= 8192 + 8*127 -> 9216
#define SLOTS_MAX 9216

typedef __attribute__((ext_vector_type(8))) short bf16x8;
typedef __attribute__((ext_vector_type(4))) float f32x4;

__device__ __forceinline__ unsigned short f2bf(float f) {
  unsigned int u = __float_as_uint(f);
  unsigned int r = (u + 0x7fffu + ((u >> 16) & 1u)) >> 16;
  return (unsigned short)r;
}

__device__ __forceinline__ void async16(const unsigned short* g, unsigned short* l) {
  __builtin_amdgcn_global_load_lds((const __attribute__((address_space(1))) void*)g,
                                   (__attribute__((address_space(3))) void*)l,
                                   16, 0, 0);
}

// ---------------- convert x: fp32 -> bf16 --------------------------------------
__global__ void convert_x_kernel(const float* __restrict__ x,
                                 unsigned short* __restrict__ xb) {
  int i = (blockIdx.x * 256 + threadIdx.x) * 4;
  float4 v = *(const float4*)(x + i);
  uint2 o;
  o.x = (unsigned int)f2bf(v.x) | ((unsigned int)f2bf(v.y) << 16);
  o.y = (unsigned int)f2bf(v.z) | ((unsigned int)f2bf(v.w) << 16);
  *(uint2*)(xb + i) = o;
}

// ------ transpose+convert: dst_bf16[e][c][r] = src_f32[e][r][coloff + c] -------
// grid: (C_sub/64, R_rows/32, NE), block 256. dst row stride = R (elements).
__global__ void transpose_kernel(const float* __restrict__ src,
                                 unsigned short* __restrict__ dst,
                                 int R, int src_stride, int col_off,
                                 size_t src_e_stride, size_t dst_e_stride) {
  __shared__ unsigned short tile[64][34];
  const float* s = src + blockIdx.z * src_e_stride;
  unsigned short* d = dst + blockIdx.z * dst_e_stride;
  const int r0 = blockIdx.y * 32;
  const int c0 = blockIdx.x * 64;
  const int t = threadIdx.x;
#pragma unroll
  for (int i = 0; i < 4; i++) {
    int row = (t >> 5) + i * 8;      // 0..31
    int cu  = t & 31;                // col unit (2 elements)
    const float2 v = *(const float2*)(s + (size_t)(r0 + row) * src_stride + col_off + c0 + cu * 2);
    tile[cu * 2][row]     = f2bf(v.x);
    tile[cu * 2 + 1][row] = f2bf(v.y);
  }
  __syncthreads();
#pragma unroll
  for (int i = 0; i < 4; i++) {
    int drow = (t >> 4) + i * 16;    // 0..63 (source col)
    int ru   = t & 15;
    unsigned int v = *(const unsigned int*)&tile[drow][ru * 2];
    *(unsigned int*)(d + (size_t)(c0 + drow) * R + r0 + ru * 2) = v;
  }
}

// ---------------- gate dots: logits, top-2, softmax (NO atomics) ---------------
__global__ void gate_dots_kernel(const float* __restrict__ inp,
                                 const float* __restrict__ gw,
                                 const float* __restrict__ gb,
                                 int2* __restrict__ tope,
                                 float2* __restrict__ tops) {
  const int tok  = blockIdx.x * 4 + (threadIdx.x >> 6);
  const int lane = threadIdx.x & 63;
  const float* x = inp + (size_t)tok * DM;
  float acc[NE];
#pragma unroll
  for (int e = 0; e < NE; e++) acc[e] = 0.f;
  for (int d = lane; d < DM; d += 64) {
    float xv = x[d];
    const float4 w0 = *(const float4*)(gw + d * NE);
    const float4 w1v = *(const float4*)(gw + d * NE + 4);
    acc[0] += xv * w0.x; acc[1] += xv * w0.y;
    acc[2] += xv * w0.z; acc[3] += xv * w0.w;
    acc[4] += xv * w1v.x; acc[5] += xv * w1v.y;
    acc[6] += xv * w1v.z; acc[7] += xv * w1v.w;
  }
#pragma unroll
  for (int e = 0; e < NE; e++) {
    float v = acc[e];
#pragma unroll
    for (int m = 32; m > 0; m >>= 1) v += __shfl_xor(v, m, 64);
    acc[e] = v + gb[e];
  }
  if (lane == 0) {
    float bv = -1e30f, sv = -1e30f; int bi = 0, si = 0;
#pragma unroll
    for (int e = 0; e < NE; e++) {
      float v = acc[e];
      if (v > bv)      { sv = bv; si = bi; bv = v; bi = e; }
      else if (v > sv) { sv = v;  si = e; }
    }
    float e1 = expf(sv - bv);
    float s0 = 1.f / (1.f + e1);
    float s1 = e1 / (1.f + e1);
    tope[tok] = make_int2(bi, si);
    tops[tok] = make_float2(s0, s1);
  }
}

// -------- assign: slot positions via LDS counters (1 block, 1024 thr) ----------
__global__ void assign_kernel(const int2* __restrict__ tope,
                              const float2* __restrict__ tops,
                              int* __restrict__ cnt,
                              int* __restrict__ base,
                              int* __restrict__ src,
                              float* __restrict__ scale) {
  __shared__ int lcnt[NE];
  const int t = threadIdx.x;
  if (t < NE) lcnt[t] = 0;
  __syncthreads();
  for (int i = t; i < NT; i += 1024) {
    int2 e = tope[i];
    float2 s = tops[i];
    int p0 = atomicAdd(&lcnt[e.x], 1);
    if (p0 < CAP) { src[e.x * CAP + p0] = i; scale[e.x * CAP + p0] = s.x; }
    int p1 = atomicAdd(&lcnt[e.y], 1);
    if (p1 < CAP) { src[e.y * CAP + p1] = i; scale[e.y * CAP + p1] = s.y; }
  }
  __syncthreads();
  if (t == 0) {
    int b = 0;
    for (int e = 0; e < NE; e++) {
      int c = min(lcnt[e], CAP);
      cnt[e] = c;
      base[e] = b;
      b += (c + 127) & ~127;
    }
  }
}

// ---------------- GEMM1: h_c = gelu(gather(xb) @ w1_chunk + b1) ---------------
// grid: (chunk/128, CAP/128, NE), block 256
__global__ __launch_bounds__(256) void gemm1_kernel(
    const unsigned short* __restrict__ xb,    // [NT][DM] bf16
    const unsigned short* __restrict__ w1t,   // [E][chunk][DM] bf16
    const float* __restrict__ b1,             // [E][HD] fp32
    const int* __restrict__ cnt,
    const int* __restrict__ base,
    const int* __restrict__ src,
    unsigned short* __restrict__ h,           // [SLOTS_MAX][chunk] bf16
    int hoff, int chunk) {
  const int e = blockIdx.z;
  const int count = cnt[e];
  const int m0 = blockIdx.y * 128;
  if (m0 >= count) return;
  const int n0 = blockIdx.x * 128;
  const int hb = base[e];

  __shared__ unsigned short As[128 * 32];   // [m][k]
  __shared__ unsigned short Bs[128 * 32];   // [n][k]

  const int t = threadIdx.x;
  const int lane = t & 63;
  const int wave = t >> 6;
  const int r0 = t >> 2;
  const int kc = (t & 3) * 8;

  const int tok0 = src[e * CAP + m0 + r0];
  const int tok1 = src[e * CAP + m0 + r0 + 64];
  const unsigned short* aptr0 = xb + (size_t)tok0 * DM + kc;
  const unsigned short* aptr1 = xb + (size_t)tok1 * DM + kc;
  const unsigned short* w1e = w1t + (size_t)e * chunk * DM;
  const unsigned short* bptr0 = w1e + (size_t)(n0 + r0) * DM + kc;
  const unsigned short* bptr1 = bptr0 + (size_t)64 * DM;

  unsigned short* as0 = As + (wave * 64) * 8;
  unsigned short* as1 = As + (256 + wave * 64) * 8;
  unsigned short* bs0 = Bs + (wave * 64) * 8;
  unsigned short* bs1 = Bs + (256 + wave * 64) * 8;

  const int wrow = (wave >> 1) * 64;
  const int wcol = (wave & 1) * 64;
  const int lrow = lane & 15;
  const int koff = (lane >> 4) * 8;

  f32x4 acc[4][4];
#pragma unroll
  for (int i = 0; i < 4; i++)
#pragma unroll
    for (int j = 0; j < 4; j++) acc[i][j] = (f32x4){0.f, 0.f, 0.f, 0.f};

  for (int k0 = 0; k0 < DM; k0 += 32) {
    async16(aptr0 + k0, as0);
    async16(aptr1 + k0, as1);
    async16(bptr0 + k0, bs0);
    async16(bptr1 + k0, bs1);
    __syncthreads();
    bf16x8 af[4], bfr[4];
#pragma unroll
    for (int i = 0; i < 4; i++)
      af[i] = *(const bf16x8*)(As + (wrow + i * 16 + lrow) * 32 + koff);
#pragma unroll
    for (int j = 0; j < 4; j++)
      bfr[j] = *(const bf16x8*)(Bs + (wcol + j * 16 + lrow) * 32 + koff);
#pragma unroll
    for (int i = 0; i < 4; i++)
#pragma unroll
      for (int j = 0; j < 4; j++)
        acc[i][j] = __builtin_amdgcn_mfma_f32_16x16x32_bf16(af[i], bfr[j], acc[i][j], 0, 0, 0);
    __syncthreads();
  }

  const int q4 = (lane >> 4) * 4;
  const int c = lane & 15;
  unsigned short* hrow = h + (size_t)(hb + m0) * chunk + n0;
#pragma unroll
  for (int j = 0; j < 4; j++) {
    const float bias = b1[e * HD + hoff + n0 + wcol + j * 16 + c];
#pragma unroll
    for (int i = 0; i < 4; i++) {
#pragma unroll
      for (int r = 0; r < 4; r++) {
        int m = wrow + i * 16 + q4 + r;
        float v = acc[i][j][r] + bias;
        float g = 0.5f * v * (1.f + tanhf(0.7978845608f * (v + 0.044715f * v * v * v)));
        hrow[(size_t)m * chunk + wcol + j * 16 + c] = f2bf(g);
      }
    }
  }
}

// ---------------- GEMM2 partial: out += scale * (h_c @ w2_chunk [+ b2]) -------
// grid: (DM/128, CAP/128, NE), block 256
__global__ __launch_bounds__(256) void gemm2_kernel(
    const unsigned short* __restrict__ h,     // [SLOTS_MAX][chunk] bf16
    const unsigned short* __restrict__ w2t,   // [E][DM][chunk] bf16
    const float* __restrict__ b2,             // [E][DM] fp32
    const int* __restrict__ cnt,
    const int* __restrict__ base,
    const int* __restrict__ src,
    const float* __restrict__ scale,
    float* __restrict__ out,                  // [NT][DM] fp32
    int chunk, int add_b2) {
  const int e = blockIdx.z;
  const int count = cnt[e];
  const int m0 = blockIdx.y * 128;
  if (m0 >= count) return;
  const int n0 = blockIdx.x * 128;
  const int hb = base[e];

  __shared__ unsigned short As[128 * 32];
  __shared__ unsigned short Bs[128 * 32];

  const int t = threadIdx.x;
  const int lane = t & 63;
  const int wave = t >> 6;
  const int r0 = t >> 2;
  const int kc = (t & 3) * 8;

  const unsigned short* aptr0 = h + (size_t)(hb + m0 + r0) * chunk + kc;
  const unsigned short* aptr1 = aptr0 + (size_t)64 * chunk;
  const unsigned short* w2e = w2t + (size_t)e * DM * chunk;
  const unsigned short* bptr0 = w2e + (size_t)(n0 + r0) * chunk + kc;
  const unsigned short* bptr1 = bptr0 + (size_t)64 * chunk;

  unsigned short* as0 = As + (wave * 64) * 8;
  unsigned short* as1 = As + (256 + wave * 64) * 8;
  unsigned short* bs0 = Bs + (wave * 64) * 8;
  unsigned short* bs1 = Bs + (256 + wave * 64) * 8;

  const int wrow = (wave >> 1) * 64;
  const int wcol = (wave & 1) * 64;
  const int lrow = lane & 15;
  const int koff = (lane >> 4) * 8;

  f32x4 acc[4][4];
#pragma unroll
  for (int i = 0; i < 4; i++)
#pragma unroll
    for (int j = 0; j < 4; j++) acc[i][j] = (f32x4){0.f, 0.f, 0.f, 0.f};

  for (int k0 = 0; k0 < chunk; k0 += 32) {
    async16(aptr0 + k0, as0);
    async16(aptr1 + k0, as1);
    async16(bptr0 + k0, bs0);
    async16(bptr1 + k0, bs1);
    __syncthreads();
    bf16x8 af[4], bfr[4];
#pragma unroll
    for (int i = 0; i < 4; i++)
      af[i] = *(const bf16x8*)(As + (wrow + i * 16 + lrow) * 32 + koff);
#pragma unroll
    for (int j = 0; j < 4; j++)
      bfr[j] = *(const bf16x8*)(Bs + (wcol + j * 16 + lrow) * 32 + koff);
#pragma unroll
    for (int i = 0; i < 4; i++)
#pragma unroll
      for (int j = 0; j < 4; j++)
        acc[i][j] = __builtin_amdgcn_mfma_f32_16x16x32_bf16(af[i], bfr[j], acc[i][j], 0, 0, 0);
    __syncthreads();
  }

  const int q4 = (lane >> 4) * 4;
  const int c = lane & 15;
#pragma unroll
  for (int i = 0; i < 4; i++) {
#pragma unroll
    for (int r = 0; r < 4; r++) {
      int m = m0 + wrow + i * 16 + q4 + r;
      float sc = scale[e * CAP + m];
      int tok = src[e * CAP + m];
      float* orow = out + (size_t)tok * DM + n0;
#pragma unroll
      for (int j = 0; j < 4; j++) {
        int n = wcol + j * 16 + c;
        float v = acc[i][j][r];
        if (add_b2) v += b2[e * DM + n0 + n];
        atomicAdd(&orow[n], sc * v);
      }
    }
  }
}

extern "C" void kernel_launch(void* const* d_in, const int* in_sizes, int n_in,
                              void* d_out, int out_size, void* d_ws, size_t ws_size,
                              hipStream_t stream) {
  const float* inp = (const float*)d_in[0];
  const float* gw  = (const float*)d_in[1];
  const float* gb  = (const float*)d_in[2];
  const float* w1  = (const float*)d_in[3];
  const float* b1  = (const float*)d_in[4];
  const float* w2  = (const float*)d_in[5];
  const float* b2  = (const float*)d_in[6];
  float* out = (float*)d_out;

  // pick largest chunk (divisor of HD, multiple of 128) whose buffers fit ws
  const int cands[8] = {3072, 1536, 1024, 768, 512, 384, 256, 128};
  int chunk = 128;
  const size_t meta = 197120; // cnt/base/src/scale/tope/tops
  for (int ci = 0; ci < 8; ci++) {
    int c = cands[ci];
    size_t need = meta + (size_t)NT * DM * 2 + 2 * (size_t)NE * c * DM * 2
                + (size_t)SLOTS_MAX * c * 2;
    if (need <= ws_size) { chunk = c; break; }
  }

  char* ws = (char*)d_ws;
  int*    cnt  = (int*)(ws);                        // 32 B
  int*    base = (int*)(ws + 256);                  // 32 B
  int*    srcb = (int*)(ws + 512);                  // 64 KB -> 66048
  float*  scl  = (float*)(ws + 66048);              // 64 KB -> 131584
  int2*   tope = (int2*)(ws + 131584);              // 32 KB -> 164352
  float2* tops = (float2*)(ws + 164352);            // 32 KB -> 197120
  size_t off = meta;
  unsigned short* xb = (unsigned short*)(ws + off);   off += (size_t)NT * DM * 2;
  unsigned short* w1tc = (unsigned short*)(ws + off); off += (size_t)NE * chunk * DM * 2;
  unsigned short* w2tc = (unsigned short*)(ws + off); off += (size_t)NE * chunk * DM * 2;
  unsigned short* hc = (unsigned short*)(ws + off);

  hipMemsetAsync(ws, 0, 131584, stream);            // cnt, base, src, scale
  hipMemsetAsync(out, 0, (size_t)NT * DM * 4, stream);

  convert_x_kernel<<<(NT * DM) / 1024, 256, 0, stream>>>(inp, xb);
  gate_dots_kernel<<<NT / 4, 256, 0, stream>>>(inp, gw, gb, tope, tops);
  assign_kernel<<<1, 1024, 0, stream>>>(tope, tops, cnt, base, srcb, scl);

  for (int c = 0; c < HD; c += chunk) {
    // w1 chunk: dst[e][h_local][d] = w1[e][d][c + h_local]
    transpose_kernel<<<dim3(chunk / 64, DM / 32, NE), 256, 0, stream>>>(
        w1, w1tc, DM, HD, c, (size_t)DM * HD, (size_t)chunk * DM);
    // w2 chunk: dst[e][d][h_local] = w2[e][c + h_local][d]
    transpose_kernel<<<dim3(DM / 64, chunk / 32, NE), 256, 0, stream>>>(
        w2 + (size_t)c * DM, w2tc, chunk, DM, 0, (size_t)HD * DM, (size_t)DM * chunk);
    gemm1_kernel<<<dim3(chunk / 128, CAP / 128, NE), 256, 0, stream>>>(
        xb, w1tc, b1, cnt, base, srcb, hc, c, chunk);
    gemm2_kernel<<<dim3(DM / 128, CAP / 128, NE), 256, 0, stream>>>(
        hc, w2tc, b2, cnt, base, srcb, scl, out, chunk, c == 0 ? 1 : 0);
  }
}

// Round 5
// 397.284 us; speedup vs baseline: 1.7141x; 1.1283x over previous
//
#include <hip/hip_runtime.h>
#include <hip/hip_bf16.h>
#include <math.h>

#define NT    4096
#define DM    768
#define HD    3072
#define NE    8
#define CAP   2048
// total compact rows: sum(roundup(min(cnt,CAP),128)) <= 8192 + 8*127 -> 9216
#define SLOTS_MAX 9216

typedef __attribute__((ext_vector_type(8))) short bf16x8;
typedef __attribute__((ext_vector_type(4))) float f32x4;

__device__ __forceinline__ unsigned short f2bf(float f) {
  unsigned int u = __float_as_uint(f);
  unsigned int r = (u + 0x7fffu + ((u >> 16) & 1u)) >> 16;
  return (unsigned short)r;
}

__device__ __forceinline__ void async16(const unsigned short* g, unsigned short* l) {
  __builtin_amdgcn_global_load_lds((const __attribute__((address_space(1))) void*)g,
                                   (__attribute__((address_space(3))) void*)l,
                                   16, 0, 0);
}

// ---------------- convert x: fp32 -> bf16 --------------------------------------
__global__ void convert_x_kernel(const float* __restrict__ x,
                                 unsigned short* __restrict__ xb) {
  int i = (blockIdx.x * 256 + threadIdx.x) * 4;
  float4 v = *(const float4*)(x + i);
  uint2 o;
  o.x = (unsigned int)f2bf(v.x) | ((unsigned int)f2bf(v.y) << 16);
  o.y = (unsigned int)f2bf(v.z) | ((unsigned int)f2bf(v.w) << 16);
  *(uint2*)(xb + i) = o;
}

// ------ transpose+convert: dst_bf16[e][c][r] = src_f32[e][r][coloff + c] -------
__global__ void transpose_kernel(const float* __restrict__ src,
                                 unsigned short* __restrict__ dst,
                                 int R, int src_stride, int col_off,
                                 size_t src_e_stride, size_t dst_e_stride) {
  __shared__ unsigned short tile[64][34];
  const float* s = src + blockIdx.z * src_e_stride;
  unsigned short* d = dst + blockIdx.z * dst_e_stride;
  const int r0 = blockIdx.y * 32;
  const int c0 = blockIdx.x * 64;
  const int t = threadIdx.x;
#pragma unroll
  for (int i = 0; i < 4; i++) {
    int row = (t >> 5) + i * 8;
    int cu  = t & 31;
    const float2 v = *(const float2*)(s + (size_t)(r0 + row) * src_stride + col_off + c0 + cu * 2);
    tile[cu * 2][row]     = f2bf(v.x);
    tile[cu * 2 + 1][row] = f2bf(v.y);
  }
  __syncthreads();
#pragma unroll
  for (int i = 0; i < 4; i++) {
    int drow = (t >> 4) + i * 16;
    int ru   = t & 15;
    unsigned int v = *(const unsigned int*)&tile[drow][ru * 2];
    *(unsigned int*)(d + (size_t)(c0 + drow) * R + r0 + ru * 2) = v;
  }
}

// ---------------- gate dots: logits, top-2, softmax (NO atomics) ---------------
__global__ void gate_dots_kernel(const float* __restrict__ inp,
                                 const float* __restrict__ gw,
                                 const float* __restrict__ gb,
                                 int2* __restrict__ tope,
                                 float2* __restrict__ tops) {
  const int tok  = blockIdx.x * 4 + (threadIdx.x >> 6);
  const int lane = threadIdx.x & 63;
  const float* x = inp + (size_t)tok * DM;
  float acc[NE];
#pragma unroll
  for (int e = 0; e < NE; e++) acc[e] = 0.f;
  for (int d = lane; d < DM; d += 64) {
    float xv = x[d];
    const float4 w0 = *(const float4*)(gw + d * NE);
    const float4 w1v = *(const float4*)(gw + d * NE + 4);
    acc[0] += xv * w0.x; acc[1] += xv * w0.y;
    acc[2] += xv * w0.z; acc[3] += xv * w0.w;
    acc[4] += xv * w1v.x; acc[5] += xv * w1v.y;
    acc[6] += xv * w1v.z; acc[7] += xv * w1v.w;
  }
#pragma unroll
  for (int e = 0; e < NE; e++) {
    float v = acc[e];
#pragma unroll
    for (int m = 32; m > 0; m >>= 1) v += __shfl_xor(v, m, 64);
    acc[e] = v + gb[e];
  }
  if (lane == 0) {
    float bv = -1e30f, sv = -1e30f; int bi = 0, si = 0;
#pragma unroll
    for (int e = 0; e < NE; e++) {
      float v = acc[e];
      if (v > bv)      { sv = bv; si = bi; bv = v; bi = e; }
      else if (v > sv) { sv = v;  si = e; }
    }
    float e1 = expf(sv - bv);
    float s0 = 1.f / (1.f + e1);
    float s1 = e1 / (1.f + e1);
    tope[tok] = make_int2(bi, si);
    tops[tok] = make_float2(s0, s1);
  }
}

// -------- assign: slot positions, ballot-aggregated LDS atomics ----------------
__device__ __forceinline__ int agg_inc(int* lcnt, int key) {
  const int lane = threadIdx.x & 63;
  int p = 0;
#pragma unroll
  for (int ee = 0; ee < NE; ee++) {
    unsigned long long m = __ballot(key == ee);
    if (m) {
      int leader = __ffsll(m) - 1;
      int n = __popcll(m);
      int b = 0;
      if (lane == leader) b = atomicAdd(&lcnt[ee], n);
      b = __shfl(b, leader, 64);
      if (key == ee) p = b + __popcll(m & ((1ull << lane) - 1ull));
    }
  }
  return p;
}

__global__ void assign_kernel(const int2* __restrict__ tope,
                              int* __restrict__ cnt,
                              int* __restrict__ base,
                              int* __restrict__ src,
                              int2* __restrict__ pos) {
  __shared__ int lcnt[NE];
  const int t = threadIdx.x;
  if (t < NE) lcnt[t] = 0;
  __syncthreads();
  for (int i = t; i < NT; i += 1024) {
    int2 e = tope[i];
    int p0 = agg_inc(lcnt, e.x);
    int p1 = agg_inc(lcnt, e.y);
    if (p0 < CAP) src[e.x * CAP + p0] = i;
    if (p1 < CAP) src[e.y * CAP + p1] = i;
    pos[i] = make_int2(p0, p1);
  }
  __syncthreads();
  if (t == 0) {
    int b = 0;
    for (int e = 0; e < NE; e++) {
      int c = min(lcnt[e], CAP);
      cnt[e] = c;
      base[e] = b;
      b += (c + 127) & ~127;
    }
  }
}

// ---------------- GEMM1: h_c = gelu(gather(xb) @ w1_chunk + b1) ---------------
// 1-D grid: NE * 16 * (chunk/128) blocks; e = b&7 (XCD-locality swizzle)
__global__ __launch_bounds__(256) void gemm1_kernel(
    const unsigned short* __restrict__ xb,    // [NT][DM] bf16
    const unsigned short* __restrict__ w1t,   // [E][chunk][DM] bf16
    const float* __restrict__ b1,             // [E][HD] fp32
    const int* __restrict__ cnt,
    const int* __restrict__ base,
    const int* __restrict__ src,
    unsigned short* __restrict__ h,           // [SLOTS_MAX][chunk] bf16
    int hoff, int chunk) {
  const int b = blockIdx.x;
  const int e = b & 7;
  const int idx = b >> 3;
  const int m0 = (idx & 15) * 128;
  const int n0 = (idx >> 4) * 128;
  const int count = cnt[e];
  if (m0 >= count) return;
  const int hb = base[e];

  __shared__ unsigned short As[128 * 32];   // [m][k]
  __shared__ unsigned short Bs[128 * 32];   // [n][k]

  const int t = threadIdx.x;
  const int lane = t & 63;
  const int wave = t >> 6;
  const int r0 = t >> 2;
  const int kc = (t & 3) * 8;

  const int tok0 = (m0 + r0      < count) ? src[e * CAP + m0 + r0]      : 0;
  const int tok1 = (m0 + r0 + 64 < count) ? src[e * CAP + m0 + r0 + 64] : 0;
  const unsigned short* aptr0 = xb + (size_t)tok0 * DM + kc;
  const unsigned short* aptr1 = xb + (size_t)tok1 * DM + kc;
  const unsigned short* w1e = w1t + (size_t)e * chunk * DM;
  const unsigned short* bptr0 = w1e + (size_t)(n0 + r0) * DM + kc;
  const unsigned short* bptr1 = bptr0 + (size_t)64 * DM;

  unsigned short* as0 = As + (wave * 64) * 8;
  unsigned short* as1 = As + (256 + wave * 64) * 8;
  unsigned short* bs0 = Bs + (wave * 64) * 8;
  unsigned short* bs1 = Bs + (256 + wave * 64) * 8;

  const int wrow = (wave >> 1) * 64;
  const int wcol = (wave & 1) * 64;
  const int lrow = lane & 15;
  const int koff = (lane >> 4) * 8;

  f32x4 acc[4][4];
#pragma unroll
  for (int i = 0; i < 4; i++)
#pragma unroll
    for (int j = 0; j < 4; j++) acc[i][j] = (f32x4){0.f, 0.f, 0.f, 0.f};

  for (int k0 = 0; k0 < DM; k0 += 32) {
    async16(aptr0 + k0, as0);
    async16(aptr1 + k0, as1);
    async16(bptr0 + k0, bs0);
    async16(bptr1 + k0, bs1);
    __syncthreads();
    bf16x8 af[4], bfr[4];
#pragma unroll
    for (int i = 0; i < 4; i++)
      af[i] = *(const bf16x8*)(As + (wrow + i * 16 + lrow) * 32 + koff);
#pragma unroll
    for (int j = 0; j < 4; j++)
      bfr[j] = *(const bf16x8*)(Bs + (wcol + j * 16 + lrow) * 32 + koff);
#pragma unroll
    for (int i = 0; i < 4; i++)
#pragma unroll
      for (int j = 0; j < 4; j++)
        acc[i][j] = __builtin_amdgcn_mfma_f32_16x16x32_bf16(af[i], bfr[j], acc[i][j], 0, 0, 0);
    __syncthreads();
  }

  const int q4 = (lane >> 4) * 4;
  const int c = lane & 15;
  unsigned short* hrow = h + (size_t)(hb + m0) * chunk + n0;
#pragma unroll
  for (int j = 0; j < 4; j++) {
    const float bias = b1[e * HD + hoff + n0 + wcol + j * 16 + c];
#pragma unroll
    for (int i = 0; i < 4; i++) {
#pragma unroll
      for (int r = 0; r < 4; r++) {
        int m = wrow + i * 16 + q4 + r;
        float v = acc[i][j][r] + bias;
        // exact identity: 0.5*v*(1+tanh(u)) == v * sigmoid(2u)
        float u2 = 1.5957691216f * (v + 0.044715f * v * v * v);
        float g = v / (1.f + __expf(-u2));
        hrow[(size_t)m * chunk + wcol + j * 16 + c] = f2bf(g);
      }
    }
  }
}

// ---------------- GEMM2: ye[slot] = h_c @ w2_chunk (+ b2 / + prev) ------------
// 1-D grid: NE * 16 * (DM/128) blocks; e = b&7
__global__ __launch_bounds__(256) void gemm2_kernel(
    const unsigned short* __restrict__ h,     // [SLOTS_MAX][chunk] bf16
    const unsigned short* __restrict__ w2t,   // [E][DM][chunk] bf16
    const float* __restrict__ b2,             // [E][DM] fp32
    const int* __restrict__ cnt,
    const int* __restrict__ base,
    float* __restrict__ ye,                   // [SLOTS_MAX][DM] fp32
    int chunk, int add_b2) {
  const int b = blockIdx.x;
  const int e = b & 7;
  const int idx = b >> 3;
  const int m0 = (idx & 15) * 128;
  const int n0 = (idx >> 4) * 128;
  const int count = cnt[e];
  if (m0 >= count) return;
  const int hb = base[e];

  __shared__ unsigned short As[128 * 32];
  __shared__ unsigned short Bs[128 * 32];

  const int t = threadIdx.x;
  const int lane = t & 63;
  const int wave = t >> 6;
  const int r0 = t >> 2;
  const int kc = (t & 3) * 8;

  const unsigned short* aptr0 = h + (size_t)(hb + m0 + r0) * chunk + kc;
  const unsigned short* aptr1 = aptr0 + (size_t)64 * chunk;
  const unsigned short* w2e = w2t + (size_t)e * DM * chunk;
  const unsigned short* bptr0 = w2e + (size_t)(n0 + r0) * chunk + kc;
  const unsigned short* bptr1 = bptr0 + (size_t)64 * chunk;

  unsigned short* as0 = As + (wave * 64) * 8;
  unsigned short* as1 = As + (256 + wave * 64) * 8;
  unsigned short* bs0 = Bs + (wave * 64) * 8;
  unsigned short* bs1 = Bs + (256 + wave * 64) * 8;

  const int wrow = (wave >> 1) * 64;
  const int wcol = (wave & 1) * 64;
  const int lrow = lane & 15;
  const int koff = (lane >> 4) * 8;

  f32x4 acc[4][4];
#pragma unroll
  for (int i = 0; i < 4; i++)
#pragma unroll
    for (int j = 0; j < 4; j++) acc[i][j] = (f32x4){0.f, 0.f, 0.f, 0.f};

  for (int k0 = 0; k0 < chunk; k0 += 32) {
    async16(aptr0 + k0, as0);
    async16(aptr1 + k0, as1);
    async16(bptr0 + k0, bs0);
    async16(bptr1 + k0, bs1);
    __syncthreads();
    bf16x8 af[4], bfr[4];
#pragma unroll
    for (int i = 0; i < 4; i++)
      af[i] = *(const bf16x8*)(As + (wrow + i * 16 + lrow) * 32 + koff);
#pragma unroll
    for (int j = 0; j < 4; j++)
      bfr[j] = *(const bf16x8*)(Bs + (wcol + j * 16 + lrow) * 32 + koff);
#pragma unroll
    for (int i = 0; i < 4; i++)
#pragma unroll
      for (int j = 0; j < 4; j++)
        acc[i][j] = __builtin_amdgcn_mfma_f32_16x16x32_bf16(af[i], bfr[j], acc[i][j], 0, 0, 0);
    __syncthreads();
  }

  const int q4 = (lane >> 4) * 4;
  const int c = lane & 15;
  float* yrow = ye + (size_t)(hb + m0) * DM + n0;
#pragma unroll
  for (int i = 0; i < 4; i++) {
#pragma unroll
    for (int r = 0; r < 4; r++) {
      int m = wrow + i * 16 + q4 + r;
#pragma unroll
      for (int j = 0; j < 4; j++) {
        int n = wcol + j * 16 + c;
        float v = acc[i][j][r];
        v += add_b2 ? b2[e * DM + n0 + n] : yrow[(size_t)m * DM + n];
        yrow[(size_t)m * DM + n] = v;
      }
    }
  }
}

// ---------------- gather: out[tok] = s0*ye[gs0] + s1*ye[gs1] -------------------
__global__ void gather_kernel(const float* __restrict__ ye,
                              const int2* __restrict__ tope,
                              const float2* __restrict__ tops,
                              const int2* __restrict__ pos,
                              const int* __restrict__ base,
                              float* __restrict__ out) {
  int idx = blockIdx.x * 256 + threadIdx.x;
  int tok = idx / (DM / 4);
  int d4 = (idx % (DM / 4)) * 4;
  int2 e = tope[tok];
  float2 s = tops[tok];
  int2 p = pos[tok];
  float4 r = make_float4(0.f, 0.f, 0.f, 0.f);
  if (p.x < CAP) {
    const float4 v = *(const float4*)(ye + (size_t)(base[e.x] + p.x) * DM + d4);
    r.x += s.x * v.x; r.y += s.x * v.y; r.z += s.x * v.z; r.w += s.x * v.w;
  }
  if (p.y < CAP) {
    const float4 v = *(const float4*)(ye + (size_t)(base[e.y] + p.y) * DM + d4);
    r.x += s.y * v.x; r.y += s.y * v.y; r.z += s.y * v.z; r.w += s.y * v.w;
  }
  *(float4*)(out + (size_t)tok * DM + d4) = r;
}

extern "C" void kernel_launch(void* const* d_in, const int* in_sizes, int n_in,
                              void* d_out, int out_size, void* d_ws, size_t ws_size,
                              hipStream_t stream) {
  const float* inp = (const float*)d_in[0];
  const float* gw  = (const float*)d_in[1];
  const float* gb  = (const float*)d_in[2];
  const float* w1  = (const float*)d_in[3];
  const float* b1  = (const float*)d_in[4];
  const float* w2  = (const float*)d_in[5];
  const float* b2  = (const float*)d_in[6];
  float* out = (float*)d_out;

  // meta layout
  const size_t meta = 164352;
  // pick largest chunk (divisor of HD, multiple of 128) whose buffers fit ws
  const int cands[8] = {3072, 1536, 1024, 768, 512, 384, 256, 128};
  int chunk = 128;
  for (int ci = 0; ci < 8; ci++) {
    int c = cands[ci];
    size_t need = meta + (size_t)NT * DM * 2                 // xb
                + 2 * (size_t)NE * c * DM * 2                // w1t + w2t
                + (size_t)SLOTS_MAX * c * 2                  // h
                + (size_t)SLOTS_MAX * DM * 4;                // ye
    if (need <= ws_size) { chunk = c; break; }
  }

  char* ws = (char*)d_ws;
  int*    cnt  = (int*)(ws);              // 256 B
  int*    base = (int*)(ws + 256);        // 256 B
  int*    srcb = (int*)(ws + 512);        // 64 KB  -> 66048
  int2*   tope = (int2*)(ws + 66048);     // 32 KB  -> 98816
  float2* tops = (float2*)(ws + 98816);   // 32 KB  -> 131584
  int2*   pos  = (int2*)(ws + 131584);    // 32 KB  -> 164352
  size_t off = meta;
  unsigned short* xb = (unsigned short*)(ws + off);   off += (size_t)NT * DM * 2;
  unsigned short* w1tc = (unsigned short*)(ws + off); off += (size_t)NE * chunk * DM * 2;
  unsigned short* w2tc = (unsigned short*)(ws + off); off += (size_t)NE * chunk * DM * 2;
  unsigned short* hc = (unsigned short*)(ws + off);   off += (size_t)SLOTS_MAX * chunk * 2;
  float* ye = (float*)(ws + off);

  convert_x_kernel<<<(NT * DM) / 1024, 256, 0, stream>>>(inp, xb);
  gate_dots_kernel<<<NT / 4, 256, 0, stream>>>(inp, gw, gb, tope, tops);
  assign_kernel<<<1, 1024, 0, stream>>>(tope, cnt, base, srcb, pos);

  for (int c = 0; c < HD; c += chunk) {
    transpose_kernel<<<dim3(chunk / 64, DM / 32, NE), 256, 0, stream>>>(
        w1, w1tc, DM, HD, c, (size_t)DM * HD, (size_t)chunk * DM);
    transpose_kernel<<<dim3(DM / 64, chunk / 32, NE), 256, 0, stream>>>(
        w2 + (size_t)c * DM, w2tc, chunk, DM, 0, (size_t)HD * DM, (size_t)DM * chunk);
    gemm1_kernel<<<NE * 16 * (chunk / 128), 256, 0, stream>>>(
        xb, w1tc, b1, cnt, base, srcb, hc, c, chunk);
    gemm2_kernel<<<NE * 16 * (DM / 128), 256, 0, stream>>>(
        hc, w2tc, b2, cnt, base, ye, chunk, c == 0 ? 1 : 0);
  }

  gather_kernel<<<(NT * DM / 4) / 256, 256, 0, stream>>>(ye, tope, tops, pos, base, out);
}

// Round 6
// 381.956 us; speedup vs baseline: 1.7829x; 1.0401x over previous
//
#include <hip/hip_runtime.h>
#include <hip/hip_bf16.h>
#include <math.h>

#define NT    4096
#define DM    768
#define HD    3072
#define NE    8
#define CAP   2048
// total compact rows: sum(roundup(min(cnt,CAP),128)) <= 8192 + 8*127 -> 9216
#define SLOTS_MAX 9216

typedef __attribute__((ext_vector_type(8))) short bf16x8;
typedef __attribute__((ext_vector_type(4))) float f32x4;

__device__ __forceinline__ unsigned short f2bf(float f) {
  unsigned int u = __float_as_uint(f);
  unsigned int r = (u + 0x7fffu + ((u >> 16) & 1u)) >> 16;
  return (unsigned short)r;
}

__device__ __forceinline__ void async16(const unsigned short* g, unsigned short* l) {
  __builtin_amdgcn_global_load_lds((const __attribute__((address_space(1))) void*)g,
                                   (__attribute__((address_space(3))) void*)l,
                                   16, 0, 0);
}

// ---------------- convert x: fp32 -> bf16 --------------------------------------
__global__ void convert_x_kernel(const float* __restrict__ x,
                                 unsigned short* __restrict__ xb) {
  int i = (blockIdx.x * 256 + threadIdx.x) * 4;
  float4 v = *(const float4*)(x + i);
  uint2 o;
  o.x = (unsigned int)f2bf(v.x) | ((unsigned int)f2bf(v.y) << 16);
  o.y = (unsigned int)f2bf(v.z) | ((unsigned int)f2bf(v.w) << 16);
  *(uint2*)(xb + i) = o;
}

// ------ transpose+convert: dst_bf16[e][c][r] = src_f32[e][r][coloff + c] -------
__global__ void transpose_kernel(const float* __restrict__ src,
                                 unsigned short* __restrict__ dst,
                                 int R, int src_stride, int col_off,
                                 size_t src_e_stride, size_t dst_e_stride) {
  __shared__ unsigned short tile[64][34];
  const float* s = src + blockIdx.z * src_e_stride;
  unsigned short* d = dst + blockIdx.z * dst_e_stride;
  const int r0 = blockIdx.y * 32;
  const int c0 = blockIdx.x * 64;
  const int t = threadIdx.x;
#pragma unroll
  for (int i = 0; i < 4; i++) {
    int row = (t >> 5) + i * 8;
    int cu  = t & 31;
    const float2 v = *(const float2*)(s + (size_t)(r0 + row) * src_stride + col_off + c0 + cu * 2);
    tile[cu * 2][row]     = f2bf(v.x);
    tile[cu * 2 + 1][row] = f2bf(v.y);
  }
  __syncthreads();
#pragma unroll
  for (int i = 0; i < 4; i++) {
    int drow = (t >> 4) + i * 16;
    int ru   = t & 15;
    unsigned int v = *(const unsigned int*)&tile[drow][ru * 2];
    *(unsigned int*)(d + (size_t)(c0 + drow) * R + r0 + ru * 2) = v;
  }
}

// ---------------- gate dots: logits, top-2, softmax (NO atomics) ---------------
__global__ void gate_dots_kernel(const float* __restrict__ inp,
                                 const float* __restrict__ gw,
                                 const float* __restrict__ gb,
                                 int2* __restrict__ tope,
                                 float2* __restrict__ tops) {
  const int tok  = blockIdx.x * 4 + (threadIdx.x >> 6);
  const int lane = threadIdx.x & 63;
  const float* x = inp + (size_t)tok * DM;
  float acc[NE];
#pragma unroll
  for (int e = 0; e < NE; e++) acc[e] = 0.f;
  for (int d = lane; d < DM; d += 64) {
    float xv = x[d];
    const float4 w0 = *(const float4*)(gw + d * NE);
    const float4 w1v = *(const float4*)(gw + d * NE + 4);
    acc[0] += xv * w0.x; acc[1] += xv * w0.y;
    acc[2] += xv * w0.z; acc[3] += xv * w0.w;
    acc[4] += xv * w1v.x; acc[5] += xv * w1v.y;
    acc[6] += xv * w1v.z; acc[7] += xv * w1v.w;
  }
#pragma unroll
  for (int e = 0; e < NE; e++) {
    float v = acc[e];
#pragma unroll
    for (int m = 32; m > 0; m >>= 1) v += __shfl_xor(v, m, 64);
    acc[e] = v + gb[e];
  }
  if (lane == 0) {
    float bv = -1e30f, sv = -1e30f; int bi = 0, si = 0;
#pragma unroll
    for (int e = 0; e < NE; e++) {
      float v = acc[e];
      if (v > bv)      { sv = bv; si = bi; bv = v; bi = e; }
      else if (v > sv) { sv = v;  si = e; }
    }
    float e1 = expf(sv - bv);
    float s0 = 1.f / (1.f + e1);
    float s1 = e1 / (1.f + e1);
    tope[tok] = make_int2(bi, si);
    tops[tok] = make_float2(s0, s1);
  }
}

// -------- assign: slot positions, ballot-aggregated LDS atomics ----------------
__device__ __forceinline__ int agg_inc(int* lcnt, int key) {
  const int lane = threadIdx.x & 63;
  int p = 0;
#pragma unroll
  for (int ee = 0; ee < NE; ee++) {
    unsigned long long m = __ballot(key == ee);
    if (m) {
      int leader = __ffsll(m) - 1;
      int n = __popcll(m);
      int b = 0;
      if (lane == leader) b = atomicAdd(&lcnt[ee], n);
      b = __shfl(b, leader, 64);
      if (key == ee) p = b + __popcll(m & ((1ull << lane) - 1ull));
    }
  }
  return p;
}

__global__ void assign_kernel(const int2* __restrict__ tope,
                              int* __restrict__ cnt,
                              int* __restrict__ base,
                              int* __restrict__ src,
                              int2* __restrict__ pos) {
  __shared__ int lcnt[NE];
  const int t = threadIdx.x;
  if (t < NE) lcnt[t] = 0;
  __syncthreads();
  for (int i = t; i < NT; i += 1024) {
    int2 e = tope[i];
    int p0 = agg_inc(lcnt, e.x);
    int p1 = agg_inc(lcnt, e.y);
    if (p0 < CAP) src[e.x * CAP + p0] = i;
    if (p1 < CAP) src[e.y * CAP + p1] = i;
    pos[i] = make_int2(p0, p1);
  }
  __syncthreads();
  if (t == 0) {
    int b = 0;
    for (int e = 0; e < NE; e++) {
      int c = min(lcnt[e], CAP);
      cnt[e] = c;
      base[e] = b;
      b += (c + 127) & ~127;
    }
  }
}

// ---------------- GEMM1: h_c = gelu(gather(xb) @ w1_chunk + b1) ---------------
// 1-D grid: NE * 16 * (chunk/128) blocks; e = b&7 (XCD-locality swizzle)
__global__ __launch_bounds__(256) void gemm1_kernel(
    const unsigned short* __restrict__ xb,    // [NT][DM] bf16
    const unsigned short* __restrict__ w1t,   // [E][chunk][DM] bf16
    const float* __restrict__ b1,             // [E][HD] fp32
    const int* __restrict__ cnt,
    const int* __restrict__ base,
    const int* __restrict__ src,
    unsigned short* __restrict__ h,           // [SLOTS_MAX][chunk] bf16
    int hoff, int chunk) {
  const int b = blockIdx.x;
  const int e = b & 7;
  const int idx = b >> 3;
  const int m0 = (idx & 15) * 128;
  const int n0 = (idx >> 4) * 128;
  const int count = cnt[e];
  if (m0 >= count) return;
  const int hb = base[e];

  __shared__ unsigned short As[128 * 32];   // [m][k]
  __shared__ unsigned short Bs[128 * 32];   // [n][k]

  const int t = threadIdx.x;
  const int lane = t & 63;
  const int wave = t >> 6;
  const int r0 = t >> 2;
  const int kc = (t & 3) * 8;

  const int tok0 = (m0 + r0      < count) ? src[e * CAP + m0 + r0]      : 0;
  const int tok1 = (m0 + r0 + 64 < count) ? src[e * CAP + m0 + r0 + 64] : 0;
  const unsigned short* aptr0 = xb + (size_t)tok0 * DM + kc;
  const unsigned short* aptr1 = xb + (size_t)tok1 * DM + kc;
  const unsigned short* w1e = w1t + (size_t)e * chunk * DM;
  const unsigned short* bptr0 = w1e + (size_t)(n0 + r0) * DM + kc;
  const unsigned short* bptr1 = bptr0 + (size_t)64 * DM;

  unsigned short* as0 = As + (wave * 64) * 8;
  unsigned short* as1 = As + (256 + wave * 64) * 8;
  unsigned short* bs0 = Bs + (wave * 64) * 8;
  unsigned short* bs1 = Bs + (256 + wave * 64) * 8;

  const int wrow = (wave >> 1) * 64;
  const int wcol = (wave & 1) * 64;
  const int lrow = lane & 15;
  const int koff = (lane >> 4) * 8;

  f32x4 acc[4][4];
#pragma unroll
  for (int i = 0; i < 4; i++)
#pragma unroll
    for (int j = 0; j < 4; j++) acc[i][j] = (f32x4){0.f, 0.f, 0.f, 0.f};

  for (int k0 = 0; k0 < DM; k0 += 32) {
    async16(aptr0 + k0, as0);
    async16(aptr1 + k0, as1);
    async16(bptr0 + k0, bs0);
    async16(bptr1 + k0, bs1);
    __syncthreads();
    bf16x8 af[4], bfr[4];
#pragma unroll
    for (int i = 0; i < 4; i++)
      af[i] = *(const bf16x8*)(As + (wrow + i * 16 + lrow) * 32 + koff);
#pragma unroll
    for (int j = 0; j < 4; j++)
      bfr[j] = *(const bf16x8*)(Bs + (wcol + j * 16 + lrow) * 32 + koff);
#pragma unroll
    for (int i = 0; i < 4; i++)
#pragma unroll
      for (int j = 0; j < 4; j++)
        acc[i][j] = __builtin_amdgcn_mfma_f32_16x16x32_bf16(af[i], bfr[j], acc[i][j], 0, 0, 0);
    __syncthreads();
  }

  const int q4 = (lane >> 4) * 4;
  const int c = lane & 15;
  unsigned short* hrow = h + (size_t)(hb + m0) * chunk + n0;
#pragma unroll
  for (int j = 0; j < 4; j++) {
    const float bias = b1[e * HD + hoff + n0 + wcol + j * 16 + c];
#pragma unroll
    for (int i = 0; i < 4; i++) {
#pragma unroll
      for (int r = 0; r < 4; r++) {
        int m = wrow + i * 16 + q4 + r;
        float v = acc[i][j][r] + bias;
        // exact identity: 0.5*v*(1+tanh(u)) == v * sigmoid(2u)
        float u2 = 1.5957691216f * (v + 0.044715f * v * v * v);
        float g = v / (1.f + __expf(-u2));
        hrow[(size_t)m * chunk + wcol + j * 16 + c] = f2bf(g);
      }
    }
  }
}

// -------- GEMM2 split-K: ye_part[kh][slot] = h_half @ w2_half (+ prev) ---------
// 1-D grid: NE * 2 * 16 * (DM/128); e = b&7, kh = (b>>3)&1
__global__ __launch_bounds__(256) void gemm2_kernel(
    const unsigned short* __restrict__ h,     // [SLOTS_MAX][chunk] bf16
    const unsigned short* __restrict__ w2t,   // [E][DM][chunk] bf16
    const int* __restrict__ cnt,
    const int* __restrict__ base,
    float* __restrict__ ye,                   // [2][SLOTS_MAX][DM] fp32
    int chunk, int add_prev) {
  const int b = blockIdx.x;
  const int e = b & 7;
  const int kh = (b >> 3) & 1;
  const int idx = b >> 4;
  const int m0 = (idx & 15) * 128;
  const int n0 = (idx >> 4) * 128;   // 0..5
  const int count = cnt[e];
  if (m0 >= count) return;
  const int hb = base[e];
  const int khalf = chunk >> 1;

  __shared__ unsigned short As[128 * 32];
  __shared__ unsigned short Bs[128 * 32];

  const int t = threadIdx.x;
  const int lane = t & 63;
  const int wave = t >> 6;
  const int r0 = t >> 2;
  const int kc = (t & 3) * 8;

  const unsigned short* aptr0 = h + (size_t)(hb + m0 + r0) * chunk + kh * khalf + kc;
  const unsigned short* aptr1 = aptr0 + (size_t)64 * chunk;
  const unsigned short* w2e = w2t + (size_t)e * DM * chunk;
  const unsigned short* bptr0 = w2e + (size_t)(n0 + r0) * chunk + kh * khalf + kc;
  const unsigned short* bptr1 = bptr0 + (size_t)64 * chunk;

  unsigned short* as0 = As + (wave * 64) * 8;
  unsigned short* as1 = As + (256 + wave * 64) * 8;
  unsigned short* bs0 = Bs + (wave * 64) * 8;
  unsigned short* bs1 = Bs + (256 + wave * 64) * 8;

  const int wrow = (wave >> 1) * 64;
  const int wcol = (wave & 1) * 64;
  const int lrow = lane & 15;
  const int koff = (lane >> 4) * 8;

  f32x4 acc[4][4];
#pragma unroll
  for (int i = 0; i < 4; i++)
#pragma unroll
    for (int j = 0; j < 4; j++) acc[i][j] = (f32x4){0.f, 0.f, 0.f, 0.f};

  for (int k0 = 0; k0 < khalf; k0 += 32) {
    async16(aptr0 + k0, as0);
    async16(aptr1 + k0, as1);
    async16(bptr0 + k0, bs0);
    async16(bptr1 + k0, bs1);
    __syncthreads();
    bf16x8 af[4], bfr[4];
#pragma unroll
    for (int i = 0; i < 4; i++)
      af[i] = *(const bf16x8*)(As + (wrow + i * 16 + lrow) * 32 + koff);
#pragma unroll
    for (int j = 0; j < 4; j++)
      bfr[j] = *(const bf16x8*)(Bs + (wcol + j * 16 + lrow) * 32 + koff);
#pragma unroll
    for (int i = 0; i < 4; i++)
#pragma unroll
      for (int j = 0; j < 4; j++)
        acc[i][j] = __builtin_amdgcn_mfma_f32_16x16x32_bf16(af[i], bfr[j], acc[i][j], 0, 0, 0);
    __syncthreads();
  }

  const int q4 = (lane >> 4) * 4;
  const int c = lane & 15;
  float* yrow = ye + (size_t)kh * SLOTS_MAX * DM + (size_t)(hb + m0) * DM + n0;
#pragma unroll
  for (int i = 0; i < 4; i++) {
#pragma unroll
    for (int r = 0; r < 4; r++) {
      int m = wrow + i * 16 + q4 + r;
#pragma unroll
      for (int j = 0; j < 4; j++) {
        int n = wcol + j * 16 + c;
        float v = acc[i][j][r];
        if (add_prev) v += yrow[(size_t)m * DM + n];
        yrow[(size_t)m * DM + n] = v;
      }
    }
  }
}

// ------- gather: out[tok] = s0*(ye0+ye1+b2)[gs0] + s1*(ye0+ye1+b2)[gs1] --------
__global__ void gather_kernel(const float* __restrict__ ye,
                              const float* __restrict__ b2,
                              const int2* __restrict__ tope,
                              const float2* __restrict__ tops,
                              const int2* __restrict__ pos,
                              const int* __restrict__ base,
                              float* __restrict__ out) {
  int idx = blockIdx.x * 256 + threadIdx.x;
  int tok = idx / (DM / 4);
  int d4 = (idx % (DM / 4)) * 4;
  int2 e = tope[tok];
  float2 s = tops[tok];
  int2 p = pos[tok];
  const float* ye1 = ye + (size_t)SLOTS_MAX * DM;
  float4 r = make_float4(0.f, 0.f, 0.f, 0.f);
  if (p.x < CAP) {
    size_t row = (size_t)(base[e.x] + p.x) * DM + d4;
    const float4 va = *(const float4*)(ye + row);
    const float4 vb = *(const float4*)(ye1 + row);
    const float4 bb = *(const float4*)(b2 + e.x * DM + d4);
    r.x += s.x * (va.x + vb.x + bb.x); r.y += s.x * (va.y + vb.y + bb.y);
    r.z += s.x * (va.z + vb.z + bb.z); r.w += s.x * (va.w + vb.w + bb.w);
  }
  if (p.y < CAP) {
    size_t row = (size_t)(base[e.y] + p.y) * DM + d4;
    const float4 va = *(const float4*)(ye + row);
    const float4 vb = *(const float4*)(ye1 + row);
    const float4 bb = *(const float4*)(b2 + e.y * DM + d4);
    r.x += s.y * (va.x + vb.x + bb.x); r.y += s.y * (va.y + vb.y + bb.y);
    r.z += s.y * (va.z + vb.z + bb.z); r.w += s.y * (va.w + vb.w + bb.w);
  }
  *(float4*)(out + (size_t)tok * DM + d4) = r;
}

extern "C" void kernel_launch(void* const* d_in, const int* in_sizes, int n_in,
                              void* d_out, int out_size, void* d_ws, size_t ws_size,
                              hipStream_t stream) {
  const float* inp = (const float*)d_in[0];
  const float* gw  = (const float*)d_in[1];
  const float* gb  = (const float*)d_in[2];
  const float* w1  = (const float*)d_in[3];
  const float* b1  = (const float*)d_in[4];
  const float* w2  = (const float*)d_in[5];
  const float* b2  = (const float*)d_in[6];
  float* out = (float*)d_out;

  const size_t meta = 164352;
  // chunk selection: one SHARED transposed-weight buffer (w1t/w2t sequential)
  const int cands[8] = {3072, 1536, 1024, 768, 512, 384, 256, 128};
  int chunk = 128;
  for (int ci = 0; ci < 8; ci++) {
    int c = cands[ci];
    size_t need = meta + (size_t)NT * DM * 2                 // xb
                + (size_t)NE * c * DM * 2                    // shared wt
                + (size_t)SLOTS_MAX * c * 2                  // h
                + 2 * (size_t)SLOTS_MAX * DM * 4;            // ye (2 partials)
    if (need <= ws_size) { chunk = c; break; }
  }

  char* ws = (char*)d_ws;
  int*    cnt  = (int*)(ws);              // 256 B
  int*    base = (int*)(ws + 256);        // 256 B
  int*    srcb = (int*)(ws + 512);        // 64 KB  -> 66048
  int2*   tope = (int2*)(ws + 66048);     // 32 KB  -> 98816
  float2* tops = (float2*)(ws + 98816);   // 32 KB  -> 131584
  int2*   pos  = (int2*)(ws + 131584);    // 32 KB  -> 164352
  size_t off = meta;
  unsigned short* xb = (unsigned short*)(ws + off);  off += (size_t)NT * DM * 2;
  unsigned short* wt = (unsigned short*)(ws + off);  off += (size_t)NE * chunk * DM * 2;
  unsigned short* hc = (unsigned short*)(ws + off);  off += (size_t)SLOTS_MAX * chunk * 2;
  float* ye = (float*)(ws + off);

  convert_x_kernel<<<(NT * DM) / 1024, 256, 0, stream>>>(inp, xb);
  gate_dots_kernel<<<NT / 4, 256, 0, stream>>>(inp, gw, gb, tope, tops);
  assign_kernel<<<1, 1024, 0, stream>>>(tope, cnt, base, srcb, pos);

  for (int c = 0; c < HD; c += chunk) {
    // w1 chunk into shared wt: wt[e][h_local][d] = w1[e][d][c + h_local]
    transpose_kernel<<<dim3(chunk / 64, DM / 32, NE), 256, 0, stream>>>(
        w1, wt, DM, HD, c, (size_t)DM * HD, (size_t)chunk * DM);
    gemm1_kernel<<<NE * 16 * (chunk / 128), 256, 0, stream>>>(
        xb, wt, b1, cnt, base, srcb, hc, c, chunk);
    // w2 chunk into the SAME wt: wt[e][d][h_local] = w2[e][c + h_local][d]
    transpose_kernel<<<dim3(DM / 64, chunk / 32, NE), 256, 0, stream>>>(
        w2 + (size_t)c * DM, wt, chunk, DM, 0, (size_t)HD * DM, (size_t)DM * chunk);
    gemm2_kernel<<<NE * 2 * 16 * (DM / 128), 256, 0, stream>>>(
        hc, wt, cnt, base, ye, chunk, c == 0 ? 0 : 1);
  }

  gather_kernel<<<(NT * DM / 4) / 256, 256, 0, stream>>>(ye, b2, tope, tops, pos, base, out);
}